// Round 9
// baseline (3591.833 us; speedup 1.0000x reference)
//
#include <hip/hip_runtime.h>
#include <hip/hip_bf16.h>

// Problem constants
#define B_ 2048
#define L_ 107
#define E_ 128
#define H_ 128
#define PRED_ 68
#define M_ (B_*L_)   // 219136 rows

typedef __bf16 bf16;
typedef __bf16 bf16x8 __attribute__((ext_vector_type(8)));
typedef __bf16 bf16x4 __attribute__((ext_vector_type(4)));
typedef float f32x4 __attribute__((ext_vector_type(4)));

__device__ __forceinline__ void gload16(const void* g, void* l) {
  __builtin_amdgcn_global_load_lds(
      (const __attribute__((address_space(1))) unsigned int*)g,
      (__attribute__((address_space(3))) unsigned int*)l, 16, 0, 0);
}

__device__ __forceinline__ float sigm(float x)  { return 1.f / (1.f + __expf(-x)); }
__device__ __forceinline__ float tanhx(float x) { return 1.f - 2.f / (1.f + __expf(2.f * x)); }

// ---------------- pack kernels ----------------
// wih pack: [gl(9)][kt(12)][nb6(6)][nt(8)][lane(64)][e(8)]  (B-fragment-linear, value = Wih[n][k])
__global__ void pack_wih_k(const float* __restrict__ w_ih, bf16* __restrict__ out) {
  int idx = blockIdx.x * 256 + threadIdx.x;
  if (idx >= 9*12*6*8*64*8) return;
  int e = idx & 7;
  int lane = (idx >> 3) & 63;
  int q = idx >> 9;
  int nt = q & 7; q >>= 3;
  int nb = q % 6; q /= 6;
  int kt = q % 12; int gl = q / 12;
  int ng = nb*128 + nt*16 + (lane & 15);     // 0..767 : [dir0 384 | dir1 384]
  int k  = kt*32 + (lane >> 4)*8 + e;        // 0..383
  int d  = (ng >= 384) ? 1 : 0;
  int np = ng - d*384;
  float v = w_ih[(((size_t)(gl*2 + d)*384 + np)*384 + k)];
  out[idx] = (bf16)v;
}

// whh pack: [gl(9)][d(2)][ks(4)][nt(24)][lane(64)][e(8)]  (value = Whh[n][k])
__global__ void pack_whh_k(const float* __restrict__ w_hh, bf16* __restrict__ out) {
  int idx = blockIdx.x * 256 + threadIdx.x;
  if (idx >= 9*2*4*24*64*8) return;
  int e = idx & 7;
  int lane = (idx >> 3) & 63;
  int q = idx >> 9;
  int nt = q % 24; q /= 24;
  int ks = q & 3;  q >>= 2;
  int d  = q & 1;  int gl = q >> 1;
  int n = nt*16 + (lane & 15);
  int k = ks*32 + (lane >> 4)*8 + e;
  out[idx] = (bf16)w_hh[((size_t)(gl*2 + d)*384 + n)*128 + k];
}

// bias pack: bias[gl][768] = bih + (n<256 ? bhh : 0); bhhn[gl][d][128] = bhh[256+j]
__global__ void pack_bias_k(const float* __restrict__ b_ih, const float* __restrict__ b_hh,
                            float* __restrict__ bias, float* __restrict__ bhhn) {
  int idx = blockIdx.x * 256 + threadIdx.x;
  if (idx < 9*768) {
    int gl = idx / 768; int n = idx % 768;
    int d = (n >= 384) ? 1 : 0; int np = n - d*384;
    float v = b_ih[(gl*2 + d)*384 + np];
    if (np < 256) v += b_hh[(gl*2 + d)*384 + np];
    bias[idx] = v;
  }
  if (idx < 9*256) {
    int gl = idx / 256; int r = idx % 256;
    int d = (r >= 128) ? 1 : 0; int j = r & 127;
    bhhn[idx] = b_hh[(gl*2 + d)*384 + 256 + j];
  }
}

// ---------------- shadow copy (per layer >=1, before phases) ----------------
// X is time-major: X[t][b][256].
// SHLO[t][b][128] = X[t][b][0:128]   (t<54,  fwd halves read late by bwd GEMM)
// SHHI[t-54][b][128] = X[t][b][128:256] (t>=54, bwd halves read late by fwd GEMM)
__global__ void shadow_k(const bf16* __restrict__ X, bf16* __restrict__ shlo,
                         bf16* __restrict__ shhi) {
  int idx = blockIdx.x * 256 + threadIdx.x;      // one 8-elem chunk each
  const int NLO = 54*2048*16;
  const int NHI = 53*2048*16;
  if (idx < NLO) {
    int k8 = idx & 15; int q = idx >> 4; int b = q & 2047; int t = q >> 11;
    *reinterpret_cast<bf16x8*>(shlo + ((size_t)t*2048 + b)*128 + k8*8) =
      *reinterpret_cast<const bf16x8*>(X + ((size_t)t*2048 + b)*256 + k8*8);
  } else {
    idx -= NLO;
    if (idx < NHI) {
      int k8 = idx & 15; int q = idx >> 4; int b = q & 2047; int t = 54 + (q >> 11);
      *reinterpret_cast<bf16x8*>(shhi + ((size_t)(t-54)*2048 + b)*128 + k8*8) =
        *reinterpret_cast<const bf16x8*>(X + ((size_t)t*2048 + b)*256 + 128 + k8*8);
    }
  }
}

// ---------------- projection GEMM (256x128 tile, R6 2-phase LDS dbuf, time-major X) ----------------
// grid (len*8, 3, 2): blockIdx.x = tw*8 + mtile (256 consecutive batch rows, uniform t).
// A-tile = contiguous 128KB slab of X[t]; staged via global_load_lds.
// Output xpw fragment-linear: [d][tile_m(=tw*128+..)][tile_n(24)][lane*4+i]
template<int L0>
__global__ __launch_bounds__(256) void gemm_proj_k(
    const bf16* __restrict__ Xin, const bf16* __restrict__ shlo, const bf16* __restrict__ shhi,
    const int* __restrict__ seq, const int* __restrict__ str, const int* __restrict__ lp,
    const float* __restrict__ table,
    const bf16* __restrict__ Bp, const float* __restrict__ bias,
    bf16* __restrict__ xpw, int len, int t0f, int t0b) {
  constexpr int KT = L0 ? 12 : 8;
  __shared__ __align__(16) bf16 As[2][256*32];
  __shared__ __align__(16) bf16 Bs[2][128*32];
  __shared__ __align__(16) bf16 TBl[L0 ? 14*136 : 8];
  __shared__ int tokl[L0 ? 3*256 : 8];
  int tid = threadIdx.x; int lane = tid & 63; int w = tid >> 6;   // wave 0..3, owns rows [64w,64w+64)
  int l4 = lane & 15, g4 = lane >> 4;
  int tw = blockIdx.x >> 3, mtile = blockIdx.x & 7;
  int nb = blockIdx.y, d = blockIdx.z;
  int t = d ? (t0b - tw) : (t0f + tw);

  // A staging: 4 chunks/thread (1024 chunks = 256 rows x 4 16B-chunks of the kt-slice)
  int sw[4];
  const bf16* pLo[4]; const bf16* pHi[4];
  #pragma unroll
  for (int i = 0; i < 4; ++i) {
    int c = tid + 256*i;
    int r = c >> 2, cc = c & 3;
    sw[i] = (cc ^ ((r >> 1) & 3)) * 8;
    int bg = mtile*256 + r;
    const bf16* xr = Xin + ((size_t)t*2048 + bg)*256;     // contiguous slab rows
    if (d == 0) {
      pLo[i] = xr;
      pHi[i] = (t < 54) ? xr : (shhi + ((size_t)(t-54)*2048 + bg)*128 - 128);
    } else {
      pHi[i] = xr;
      pLo[i] = (t < 54) ? (shlo + ((size_t)t*2048 + bg)*128) : xr;
    }
  }
  int c0 = tid, c1 = tid + 256;   // B staging: 2 chunks/thread (512 chunks)
  const bf16* Bb = Bp + (size_t)(d*3 + nb) * 4096;

  if constexpr (L0) {
    for (int i = tid; i < 1792; i += 256) TBl[(i >> 7)*136 + (i & 127)] = (bf16)table[i];
    for (int i = tid; i < 768; i += 256) {
      int b = mtile*256 + (i & 255);
      const int* tokp = (i < 256) ? seq : ((i < 512) ? str : lp);
      tokl[i] = tokp[b*107 + t];
    }
  }

  float bias_r[8];
  #pragma unroll
  for (int nt = 0; nt < 8; ++nt)
    bias_r[nt] = bias[d*384 + nb*128 + nt*16 + l4];

  f32x4 acc[4][8];
  #pragma unroll
  for (int i = 0; i < 4; ++i)
    #pragma unroll
    for (int j = 0; j < 8; ++j) { f32x4 z = {0.f,0.f,0.f,0.f}; acc[i][j] = z; }

  // prologue: stage kt=0 into buf 0  (L0 stages B only)
  if constexpr (!L0) {
    #pragma unroll
    for (int i = 0; i < 4; ++i)
      gload16(pLo[i] + sw[i], &As[0][(tid + 256*i)*8]);
  }
  gload16(Bb + c0*8, &Bs[0][c0*8]);
  gload16(Bb + c1*8, &Bs[0][c1*8]);
  __syncthreads();

  for (int kt = 0; kt < KT; ++kt) {
    int cur = kt & 1, nxt = cur ^ 1;
    if (kt + 1 < KT) {           // stage kt+1 (in flight during MFMA below)
      int k1 = kt + 1;
      if constexpr (!L0) {
        #pragma unroll
        for (int i = 0; i < 4; ++i)
          gload16((k1 < 4 ? pLo[i] : pHi[i]) + (size_t)k1*32 + sw[i], &As[nxt][(tid + 256*i)*8]);
      }
      gload16(Bb + (size_t)k1*6*4096 + c0*8, &Bs[nxt][c0*8]);
      gload16(Bb + (size_t)k1*6*4096 + c1*8, &Bs[nxt][c1*8]);
    }
    bf16x8 af[4], bfr[8];
    if constexpr (L0) {
      int ch = kt >> 2; int kc = (kt & 3) * 32;
      #pragma unroll
      for (int mt = 0; mt < 4; ++mt) {
        int r = w*64 + mt*16 + l4;
        af[mt] = *reinterpret_cast<const bf16x8*>(TBl + tokl[ch*256 + r]*136 + kc + g4*8);
      }
    } else {
      #pragma unroll
      for (int mt = 0; mt < 4; ++mt) {
        int r = w*64 + mt*16 + l4;
        af[mt] = *reinterpret_cast<const bf16x8*>(&As[cur][r*32 + ((g4 ^ ((r >> 1) & 3)) * 8)]);
      }
    }
    #pragma unroll
    for (int nt = 0; nt < 8; ++nt)
      bfr[nt] = *reinterpret_cast<const bf16x8*>(&Bs[cur][(nt*64 + lane)*8]);
    #pragma unroll
    for (int mt = 0; mt < 4; ++mt)
      #pragma unroll
      for (int nt = 0; nt < 8; ++nt)
        acc[mt][nt] = __builtin_amdgcn_mfma_f32_16x16x32_bf16(af[mt], bfr[nt], acc[mt][nt], 0, 0, 0);
    __syncthreads();   // drains next-stage loads (implicit vmcnt0) + publishes LDS
  }

  // epilogue: fragment-linear bf16x4 stores
  int tile_m_base = tw*128 + mtile*16 + w*4;
  int tile_n_base = nb*8;
  size_t dbase = d ? (size_t)len*128*24*256 : 0;
  #pragma unroll
  for (int mt = 0; mt < 4; ++mt)
    #pragma unroll
    for (int nt = 0; nt < 8; ++nt) {
      f32x4 a = acc[mt][nt]; float bv = bias_r[nt];
      bf16x4 o;
      o[0] = (bf16)(a[0] + bv); o[1] = (bf16)(a[1] + bv);
      o[2] = (bf16)(a[2] + bv); o[3] = (bf16)(a[3] + bv);
      *reinterpret_cast<bf16x4*>(xpw + dbase +
          (((size_t)(tile_m_base + mt)*24 + tile_n_base + nt) << 8) + lane*4) = o;
    }
}

// ---------------- GRU scan (one layer, one time window, full batch) ----------------
// grid (128, 2), 512 threads (8 waves, 2/SIMD): 16 batch rows/block;
// wave w owns h-cols [16w,16w+16) -> MFMA n-tiles {w, 8+w, 16+w} (r,z,n).
// xout is time-major X[t][b][256].
__global__ __launch_bounds__(512, 1) void scan_k(const bf16* __restrict__ xpw,
                                                 const bf16* __restrict__ whh,
                                                 const float* __restrict__ bhhn,
                                                 bf16* __restrict__ xout,
                                                 float* __restrict__ hst,
                                                 int len, int t0f, int t0b, int first) {
  __shared__ __align__(16) bf16 h_lds[2][2048];  // A-fragment order: [ks(4)][lane(64)][e(8)]
  int tid = threadIdx.x; int lane = tid & 63; int w = tid >> 6;   // 0..7
  int l4 = lane & 15, g4 = lane >> 4;
  int d = blockIdx.y;
  int bx = blockIdx.x;
  int b0 = bx * 16;
  const bf16* xpb = xpw + (d ? (size_t)len*128*24*256 : 0);
  int ntl[3] = { w, 8 + w, 16 + w };
  int fragoff = g4*64 + l4*4;
  int j = w*16 + l4;                 // owned h-col
  int js = j >> 5, jc3 = (j >> 3) & 3, je = j & 7;

  // Whh B-fragments in registers (constant over time): 3 n-tiles x 4 k-slices
  bf16x8 bw[3][4];
  #pragma unroll
  for (int nt = 0; nt < 3; ++nt)
    #pragma unroll
    for (int ks = 0; ks < 4; ++ks)
      bw[nt][ks] = *reinterpret_cast<const bf16x8*>(whh + ((size_t)(d*4 + ks)*24 + ntl[nt])*512 + lane*8);

  float bn = bhhn[d*128 + j];
  float h_own[4];

  if (first) {
    #pragma unroll
    for (int i = 0; i < 4; ++i) h_own[i] = 0.f;
    if (tid < 256) reinterpret_cast<float4*>(&h_lds[0][0])[tid] = make_float4(0.f, 0.f, 0.f, 0.f);
  } else {
    #pragma unroll
    for (int i = 0; i < 4; ++i) {
      h_own[i] = hst[((size_t)d*2048 + b0 + g4*4 + i)*128 + j];
      int m = g4*4 + i;
      h_lds[0][(js*64 + m + 16*jc3)*8 + je] = (bf16)h_own[i];
    }
  }

  bf16x4 xa[3], xb[3];
  { // prologue: load xp for tw=0 (tile_m = bx)
    #pragma unroll
    for (int nt = 0; nt < 3; ++nt)
      xa[nt] = *reinterpret_cast<const bf16x4*>(xpb + (((size_t)bx*24 + ntl[nt]) << 8) + fragoff);
  }
  __syncthreads();

  auto step = [&](bf16x4 (&xu)[3], bf16x4 (&xl)[3], int tw, int pb) {
    int tc = d ? (t0b - tw) : (t0f + tw);
    int twn = (tw + 1 < len) ? (tw + 1) : (len - 1);
    // A-fragments of h from LDS (fragment-linear, conflict-free)
    bf16x8 a[4];
    #pragma unroll
    for (int ks = 0; ks < 4; ++ks)
      a[ks] = *reinterpret_cast<const bf16x8*>(&h_lds[pb][(ks*64 + lane)*8]);
    // prefetch next step's xp (vector; latency hidden under MFMA+gates)
    size_t tmn = (size_t)(twn*128 + bx)*24;
    #pragma unroll
    for (int nt = 0; nt < 3; ++nt)
      xl[nt] = *reinterpret_cast<const bf16x4*>(xpb + ((tmn + ntl[nt]) << 8) + fragoff);
    // gh = h @ Whh^T  (3 n-tiles: r,z,n for this wave's col group)
    f32x4 acc[3];
    #pragma unroll
    for (int nt = 0; nt < 3; ++nt) { f32x4 z = {0.f,0.f,0.f,0.f}; acc[nt] = z; }
    #pragma unroll
    for (int ks = 0; ks < 4; ++ks)
      #pragma unroll
      for (int nt = 0; nt < 3; ++nt)
        acc[nt] = __builtin_amdgcn_mfma_f32_16x16x32_bf16(a[ks], bw[nt][ks], acc[nt], 0, 0, 0);
    // gates (4 rows x 1 col per thread)
    #pragma unroll
    for (int i = 0; i < 4; ++i) {
      float r = sigm((float)xu[0][i] + acc[0][i]);          // bih+bhh folded into xp
      float z = sigm((float)xu[1][i] + acc[1][i]);
      float n = tanhx((float)xu[2][i] + r * (acc[2][i] + bn));  // bhh_n inside r*( )
      float hv = (1.f - z) * n + z * h_own[i];
      h_own[i] = hv;
      int m = g4*4 + i;
      h_lds[pb ^ 1][(js*64 + m + 16*jc3)*8 + je] = (bf16)hv;
    }
    __syncthreads();   // new-h visible to all
    // repacked X write (time-major): 16B per thread (first 4 waves) from h_lds[pb^1]
    if (tid < 256) {
      int mo = tid & 15, sc = tid >> 4;
      int s = sc >> 2, c3 = sc & 3;
      bf16x8 v = *reinterpret_cast<const bf16x8*>(&h_lds[pb ^ 1][s*512 + c3*128 + mo*8]);
      *reinterpret_cast<bf16x8*>(xout + ((size_t)tc*2048 + b0 + mo)*256 + d*128 + s*32 + c3*8) = v;
    }
  };

  for (int tw = 0; tw < len; ++tw) {
    if (tw & 1) step(xb, xa, tw, 1);
    else        step(xa, xb, tw, 0);
  }
  // persist h state
  #pragma unroll
  for (int i = 0; i < 4; ++i)
    hst[((size_t)d*2048 + b0 + g4*4 + i)*128 + j] = h_own[i];
}

// ---------------- final linear ----------------
__global__ void final_k(const bf16* __restrict__ hs, const float* __restrict__ lw,
                        const float* __restrict__ lb, float* __restrict__ out) {
  __shared__ float wsm[768];
  int tid = threadIdx.x;
  for (int i = tid; i < 768; i += 256) wsm[i] = lw[i];
  __syncthreads();
  int idx = blockIdx.x * 256 + tid;           // 0..139263  (b*68 + t)
  int b = idx / 68, t = idx % 68;
  const bf16* row = hs + ((size_t)t*2048 + b) * 256;   // time-major X
  float a0 = lb[0], a1 = lb[1], a2 = lb[2];
  for (int j0 = 0; j0 < 256; j0 += 8) {
    bf16x8 v = *reinterpret_cast<const bf16x8*>(row + j0);
    #pragma unroll
    for (int e = 0; e < 8; ++e) {
      float f = (float)v[e];
      a0 += f * wsm[(j0 + e)*3 + 0];
      a1 += f * wsm[(j0 + e)*3 + 1];
      a2 += f * wsm[(j0 + e)*3 + 2];
    }
  }
  out[(size_t)idx*3 + 0] = a0;
  out[(size_t)idx*3 + 1] = a1;
  out[(size_t)idx*3 + 2] = a2;
}

// ---------------- launch ----------------
extern "C" void kernel_launch(void* const* d_in, const int* in_sizes, int n_in,
                              void* d_out, int out_size, void* d_ws, size_t ws_size,
                              hipStream_t stream) {
  const int*   seq   = (const int*)d_in[0];
  const int*   str   = (const int*)d_in[1];
  const int*   lp    = (const int*)d_in[2];
  const float* table = (const float*)d_in[3];
  const float* w_ih  = (const float*)d_in[4];
  const float* w_hh  = (const float*)d_in[5];
  const float* b_ih  = (const float*)d_in[6];
  const float* b_hh  = (const float*)d_in[7];
  const float* lw    = (const float*)d_in[8];
  const float* lb    = (const float*)d_in[9];
  float* out = (float*)d_out;
  char* ws = (char*)d_ws;

  // ---- layout ----
  const size_t xsz    = (size_t)M_ * 256 * 2;        // 112,197,632 (X, time-major)
  const size_t shlosz = (size_t)54*2048*128*2;       // 28,311,552
  const size_t shhisz = (size_t)53*2048*128*2;       // 27,787,264
  const size_t wihsz  = (size_t)9*12*6*8*64*8 * 2;   // 5,308,416
  const size_t whhsz  = (size_t)9*2*4*24*64*8 * 2;   // 1,769,472
  const size_t biassz = 9*768*4, bhhnsz = 9*256*4;
  const size_t hstsz  = (size_t)2*2048*128*4;        // 2,097,152
  const size_t fixed  = xsz + shlosz + shhisz + wihsz + whhsz + biassz + bhhnsz + hstsz;
  int W = 32;
  while (W > 8 && fixed + (size_t)2*2048*W*384*2 > ws_size) W -= 8;
  const size_t xpwsz = (size_t)2*2048*W*384*2;

  size_t off = 0;
  bf16* X    = (bf16*)(ws + off); off += xsz;
  bf16* XPW  = (bf16*)(ws + off); off += xpwsz;
  bf16* SHLO = (bf16*)(ws + off); off += shlosz;
  bf16* SHHI = (bf16*)(ws + off); off += shhisz;
  bf16* WIH  = (bf16*)(ws + off); off += wihsz;
  bf16* WHH  = (bf16*)(ws + off); off += whhsz;
  float* BIAS = (float*)(ws + off); off += biassz;
  float* BHHN = (float*)(ws + off); off += bhhnsz;
  float* HST  = (float*)(ws + off);

  hipLaunchKernelGGL(pack_wih_k,  dim3(2654208/256), dim3(256), 0, stream, w_ih, WIH);
  hipLaunchKernelGGL(pack_whh_k,  dim3(884736/256),  dim3(256), 0, stream, w_hh, WHH);
  hipLaunchKernelGGL(pack_bias_k, dim3(27),          dim3(256), 0, stream, b_ih, b_hh, BIAS, BHHN);

  const int phases = (107 + W - 1) / W;
  for (int gl = 0; gl < 9; ++gl) {
    if (gl != 0)
      hipLaunchKernelGGL(shadow_k, dim3(13696), dim3(256), 0, stream, X, SHLO, SHHI);
    for (int p = 0; p < phases; ++p) {
      int len = (107 - p*W < W) ? (107 - p*W) : W;
      int t0f = p*W;
      int t0b = 106 - p*W;
      if (gl == 0)
        hipLaunchKernelGGL(gemm_proj_k<1>, dim3(len*8, 3, 2), dim3(256), 0, stream,
                           X, SHLO, SHHI, seq, str, lp, table,
                           WIH + (size_t)gl*294912, BIAS + gl*768, XPW, len, t0f, t0b);
      else
        hipLaunchKernelGGL(gemm_proj_k<0>, dim3(len*8, 3, 2), dim3(256), 0, stream,
                           X, SHLO, SHHI, seq, str, lp, table,
                           WIH + (size_t)gl*294912, BIAS + gl*768, XPW, len, t0f, t0b);
      hipLaunchKernelGGL(scan_k, dim3(128, 2), dim3(512), 0, stream,
                         XPW, WHH + (size_t)gl*98304, BHHN + gl*256, X, HST,
                         len, t0f, t0b, (p == 0) ? 1 : 0);
    }
  }
  hipLaunchKernelGGL(final_k, dim3(544), dim3(256), 0, stream, X, lw, lb, out);
}

// Round 10
// 2962.287 us; speedup vs baseline: 1.2125x; 1.2125x over previous
//
#include <hip/hip_runtime.h>
#include <hip/hip_bf16.h>

// Problem constants
#define B_ 2048
#define L_ 107
#define E_ 128
#define H_ 128
#define PRED_ 68
#define M_ (B_*L_)   // 219136 rows

typedef __bf16 bf16;
typedef __bf16 bf16x8 __attribute__((ext_vector_type(8)));
typedef __bf16 bf16x4 __attribute__((ext_vector_type(4)));
typedef float f32x4 __attribute__((ext_vector_type(4)));

__device__ __forceinline__ void gload16(const void* g, void* l) {
  __builtin_amdgcn_global_load_lds(
      (const __attribute__((address_space(1))) unsigned int*)g,
      (__attribute__((address_space(3))) unsigned int*)l, 16, 0, 0);
}

__device__ __forceinline__ float sigm(float x)  { return 1.f / (1.f + __expf(-x)); }
__device__ __forceinline__ float tanhx(float x) { return 1.f - 2.f / (1.f + __expf(2.f * x)); }

// ---------------- pack kernels ----------------
// wih pack: [gl(9)][kt(12)][nb6(6)][nt(8)][lane(64)][e(8)]  (B-fragment-linear, value = Wih[n][k])
__global__ void pack_wih_k(const float* __restrict__ w_ih, bf16* __restrict__ out) {
  int idx = blockIdx.x * 256 + threadIdx.x;
  if (idx >= 9*12*6*8*64*8) return;
  int e = idx & 7;
  int lane = (idx >> 3) & 63;
  int q = idx >> 9;
  int nt = q & 7; q >>= 3;
  int nb = q % 6; q /= 6;
  int kt = q % 12; int gl = q / 12;
  int ng = nb*128 + nt*16 + (lane & 15);     // 0..767 : [dir0 384 | dir1 384]
  int k  = kt*32 + (lane >> 4)*8 + e;        // 0..383
  int d  = (ng >= 384) ? 1 : 0;
  int np = ng - d*384;
  float v = w_ih[(((size_t)(gl*2 + d)*384 + np)*384 + k)];
  out[idx] = (bf16)v;
}

// whh pack: [gl(9)][d(2)][ks(4)][nt(24)][lane(64)][e(8)]  (value = Whh[n][k])
__global__ void pack_whh_k(const float* __restrict__ w_hh, bf16* __restrict__ out) {
  int idx = blockIdx.x * 256 + threadIdx.x;
  if (idx >= 9*2*4*24*64*8) return;
  int e = idx & 7;
  int lane = (idx >> 3) & 63;
  int q = idx >> 9;
  int nt = q % 24; q /= 24;
  int ks = q & 3;  q >>= 2;
  int d  = q & 1;  int gl = q >> 1;
  int n = nt*16 + (lane & 15);
  int k = ks*32 + (lane >> 4)*8 + e;
  out[idx] = (bf16)w_hh[((size_t)(gl*2 + d)*384 + n)*128 + k];
}

// bias pack: bias[gl][768] = bih + (n<256 ? bhh : 0); bhhn[gl][d][128] = bhh[256+j]
__global__ void pack_bias_k(const float* __restrict__ b_ih, const float* __restrict__ b_hh,
                            float* __restrict__ bias, float* __restrict__ bhhn) {
  int idx = blockIdx.x * 256 + threadIdx.x;
  if (idx < 9*768) {
    int gl = idx / 768; int n = idx % 768;
    int d = (n >= 384) ? 1 : 0; int np = n - d*384;
    float v = b_ih[(gl*2 + d)*384 + np];
    if (np < 256) v += b_hh[(gl*2 + d)*384 + np];
    bias[idx] = v;
  }
  if (idx < 9*256) {
    int gl = idx / 256; int r = idx % 256;
    int d = (r >= 128) ? 1 : 0; int j = r & 127;
    bhhn[idx] = b_hh[(gl*2 + d)*384 + 256 + j];
  }
}

// ---------------- shadow copy (per layer >=1, before phases) ----------------
// X is time-major: X[t][b][256].
// SHLO[t][b][128] = X[t][b][0:128]   (t<54,  fwd halves read late by bwd GEMM)
// SHHI[t-54][b][128] = X[t][b][128:256] (t>=54, bwd halves read late by fwd GEMM)
__global__ void shadow_k(const bf16* __restrict__ X, bf16* __restrict__ shlo,
                         bf16* __restrict__ shhi) {
  int idx = blockIdx.x * 256 + threadIdx.x;      // one 8-elem chunk each
  const int NLO = 54*2048*16;
  const int NHI = 53*2048*16;
  if (idx < NLO) {
    int k8 = idx & 15; int q = idx >> 4; int b = q & 2047; int t = q >> 11;
    *reinterpret_cast<bf16x8*>(shlo + ((size_t)t*2048 + b)*128 + k8*8) =
      *reinterpret_cast<const bf16x8*>(X + ((size_t)t*2048 + b)*256 + k8*8);
  } else {
    idx -= NLO;
    if (idx < NHI) {
      int k8 = idx & 15; int q = idx >> 4; int b = q & 2047; int t = 54 + (q >> 11);
      *reinterpret_cast<bf16x8*>(shhi + ((size_t)(t-54)*2048 + b)*128 + k8*8) =
        *reinterpret_cast<const bf16x8*>(X + ((size_t)t*2048 + b)*256 + 128 + k8*8);
    }
  }
}

// ---------------- projection GEMM (A staged once, B global->reg, barrier-free K-loop) ----------------
// grid (len*16, 2): blockIdx.x = tw*16 + mtile (128 batch rows, uniform t); blockIdx.y = d.
// A: 128x256 slab staged to 64KB LDS once (XOR-swizzled chunks), single barrier.
// B: fragment-linear packed WIH read per-wave straight into registers (L2-hot), dbuf.
// nb=0..2 folded into the block: 3 x (8|12 kt x 16 MFMA) with zero barriers.
// Output xpw fragment-linear: [d][tile_m][tile_n(24)][lane*4+i]
template<int L0>
__global__ __launch_bounds__(256) void gemm_proj_k(
    const bf16* __restrict__ Xin, const bf16* __restrict__ shlo, const bf16* __restrict__ shhi,
    const int* __restrict__ seq, const int* __restrict__ str, const int* __restrict__ lp,
    const float* __restrict__ table,
    const bf16* __restrict__ Bp, const float* __restrict__ bias,
    bf16* __restrict__ xpw, int len, int t0f, int t0b) {
  constexpr int KT = L0 ? 12 : 8;
  __shared__ __align__(16) bf16 As[L0 ? 8 : 128*256];   // 64KB (layers>=1)
  __shared__ __align__(16) bf16 TBl[L0 ? 14*136 : 8];
  __shared__ int tokl[L0 ? 3*128 : 8];
  int tid = threadIdx.x; int lane = tid & 63; int w = tid >> 6;
  int l4 = lane & 15, g4 = lane >> 4;
  int wm = w >> 1, wn = w & 1;
  int tw = blockIdx.x >> 4, mtile = blockIdx.x & 15;
  int d = blockIdx.y;
  int t = d ? (t0b - tw) : (t0f + tw);

  if constexpr (L0) {
    for (int i = tid; i < 1792; i += 256) TBl[(i >> 7)*136 + (i & 127)] = (bf16)table[i];
    if (tid < 128) {
      int b = mtile*128 + tid;
      int g = b*107 + t;
      tokl[tid] = seq[g]; tokl[128 + tid] = str[g]; tokl[256 + tid] = lp[g];
    }
    __syncthreads();
  } else {
    // stage A once: 128 rows x 32 chunks(16B); chunk slot cs holds source chunk
    // sc = (cs & ~3) | ((cs&3) ^ ((r>>1)&3))  (XOR within each kt group of 4)
    #pragma unroll
    for (int i = 0; i < 16; ++i) {
      int id = tid + 256*i;
      int r = id >> 5, cs = id & 31;
      int sc = (cs & ~3) | ((cs & 3) ^ ((r >> 1) & 3));
      int bg = mtile*128 + r;
      const bf16* xr = Xin + ((size_t)t*2048 + bg)*256;
      const bf16* src;
      if (sc < 16) {   // cols 0..127 (lo half)
        src = (d == 0) ? xr
              : ((t < 54) ? (shlo + ((size_t)t*2048 + bg)*128) : xr);
      } else {         // cols 128..255 (hi half)
        src = (d == 0) ? ((t < 54) ? xr : (shhi + ((size_t)(t-54)*2048 + bg)*128 - 128))
              : xr;
      }
      gload16(src + sc*8, As + (size_t)id*8);
    }
    __syncthreads();
  }

  float bias_r[3][4];
  #pragma unroll
  for (int nb = 0; nb < 3; ++nb)
    #pragma unroll
    for (int nt = 0; nt < 4; ++nt)
      bias_r[nb][nt] = bias[d*384 + nb*128 + wn*64 + nt*16 + l4];

  // B fragment loader: straight from global (fragment-linear pack, coalesced 1KB/wave)
  auto loadB = [&](bf16x8 (&dst)[4], int nb, int kt) {
    #pragma unroll
    for (int nt = 0; nt < 4; ++nt)
      dst[nt] = *reinterpret_cast<const bf16x8*>(
          Bp + (((size_t)(kt*6 + d*3 + nb)*8 + wn*4 + nt) << 9) + lane*8);
  };
  auto loadA = [&](bf16x8 (&af)[4], int kt) {
    if constexpr (L0) {
      int ch = kt >> 2, kc = (kt & 3) * 32;
      #pragma unroll
      for (int mt = 0; mt < 4; ++mt)
        af[mt] = *reinterpret_cast<const bf16x8*>(
            TBl + tokl[ch*128 + wm*64 + mt*16 + l4]*136 + kc + g4*8);
    } else {
      #pragma unroll
      for (int mt = 0; mt < 4; ++mt) {
        int r = wm*64 + mt*16 + l4;
        int cs = kt*4 + (g4 ^ ((r >> 1) & 3));
        af[mt] = *reinterpret_cast<const bf16x8*>(As + (size_t)(r*32 + cs)*8);
      }
    }
  };

  int tile_m_base = tw*128 + mtile*8 + wm*4;
  size_t dbase = d ? (size_t)len*128*24*256 : 0;

  bf16x8 bf0[4], bf1[4], af[4];
  loadB(bf0, 0, 0);
  #pragma unroll
  for (int nb = 0; nb < 3; ++nb) {
    f32x4 acc[4][4];
    #pragma unroll
    for (int i = 0; i < 4; ++i)
      #pragma unroll
      for (int j = 0; j < 4; ++j) { f32x4 z = {0.f,0.f,0.f,0.f}; acc[i][j] = z; }
    #pragma unroll
    for (int kt = 0; kt < KT; ++kt) {
      // prefetch next B fragment set (next kt, or next nb's kt=0)
      if (kt + 1 < KT)      loadB(bf1, nb, kt + 1);
      else if (nb + 1 < 3)  loadB(bf1, nb + 1, 0);
      loadA(af, kt);
      #pragma unroll
      for (int mt = 0; mt < 4; ++mt)
        #pragma unroll
        for (int nt = 0; nt < 4; ++nt)
          acc[mt][nt] = __builtin_amdgcn_mfma_f32_16x16x32_bf16(af[mt], bf0[nt], acc[mt][nt], 0, 0, 0);
      #pragma unroll
      for (int q = 0; q < 4; ++q) bf0[q] = bf1[q];
    }
    // epilogue for this nb: fragment-linear bf16x4 stores
    int tile_n_base = nb*8 + wn*4;
    #pragma unroll
    for (int mt = 0; mt < 4; ++mt)
      #pragma unroll
      for (int nt = 0; nt < 4; ++nt) {
        f32x4 a = acc[mt][nt]; float bv = bias_r[nb][nt];
        bf16x4 o;
        o[0] = (bf16)(a[0] + bv); o[1] = (bf16)(a[1] + bv);
        o[2] = (bf16)(a[2] + bv); o[3] = (bf16)(a[3] + bv);
        *reinterpret_cast<bf16x4*>(xpw + dbase +
            (((size_t)(tile_m_base + mt)*24 + tile_n_base + nt) << 8) + lane*4) = o;
      }
  }
}

// ---------------- GRU scan (one layer, one time window, full batch) ----------------
// grid (128, 2), 512 threads (8 waves, 2/SIMD): 16 batch rows/block;
// wave w owns h-cols [16w,16w+16) -> MFMA n-tiles {w, 8+w, 16+w} (r,z,n).
// xout is time-major X[t][b][256].
__global__ __launch_bounds__(512, 1) void scan_k(const bf16* __restrict__ xpw,
                                                 const bf16* __restrict__ whh,
                                                 const float* __restrict__ bhhn,
                                                 bf16* __restrict__ xout,
                                                 float* __restrict__ hst,
                                                 int len, int t0f, int t0b, int first) {
  __shared__ __align__(16) bf16 h_lds[2][2048];  // A-fragment order: [ks(4)][lane(64)][e(8)]
  int tid = threadIdx.x; int lane = tid & 63; int w = tid >> 6;   // 0..7
  int l4 = lane & 15, g4 = lane >> 4;
  int d = blockIdx.y;
  int bx = blockIdx.x;
  int b0 = bx * 16;
  const bf16* xpb = xpw + (d ? (size_t)len*128*24*256 : 0);
  int ntl[3] = { w, 8 + w, 16 + w };
  int fragoff = g4*64 + l4*4;
  int j = w*16 + l4;                 // owned h-col
  int js = j >> 5, jc3 = (j >> 3) & 3, je = j & 7;

  // Whh B-fragments in registers (constant over time): 3 n-tiles x 4 k-slices
  bf16x8 bw[3][4];
  #pragma unroll
  for (int nt = 0; nt < 3; ++nt)
    #pragma unroll
    for (int ks = 0; ks < 4; ++ks)
      bw[nt][ks] = *reinterpret_cast<const bf16x8*>(whh + ((size_t)(d*4 + ks)*24 + ntl[nt])*512 + lane*8);

  float bn = bhhn[d*128 + j];
  float h_own[4];

  if (first) {
    #pragma unroll
    for (int i = 0; i < 4; ++i) h_own[i] = 0.f;
    if (tid < 256) reinterpret_cast<float4*>(&h_lds[0][0])[tid] = make_float4(0.f, 0.f, 0.f, 0.f);
  } else {
    #pragma unroll
    for (int i = 0; i < 4; ++i) {
      h_own[i] = hst[((size_t)d*2048 + b0 + g4*4 + i)*128 + j];
      int m = g4*4 + i;
      h_lds[0][(js*64 + m + 16*jc3)*8 + je] = (bf16)h_own[i];
    }
  }

  bf16x4 xa[3], xb[3];
  { // prologue: load xp for tw=0 (tile_m = bx)
    #pragma unroll
    for (int nt = 0; nt < 3; ++nt)
      xa[nt] = *reinterpret_cast<const bf16x4*>(xpb + (((size_t)bx*24 + ntl[nt]) << 8) + fragoff);
  }
  __syncthreads();

  auto step = [&](bf16x4 (&xu)[3], bf16x4 (&xl)[3], int tw, int pb) {
    int tc = d ? (t0b - tw) : (t0f + tw);
    int twn = (tw + 1 < len) ? (tw + 1) : (len - 1);
    // A-fragments of h from LDS (fragment-linear, conflict-free)
    bf16x8 a[4];
    #pragma unroll
    for (int ks = 0; ks < 4; ++ks)
      a[ks] = *reinterpret_cast<const bf16x8*>(&h_lds[pb][(ks*64 + lane)*8]);
    // prefetch next step's xp (vector; latency hidden under MFMA+gates)
    size_t tmn = (size_t)(twn*128 + bx)*24;
    #pragma unroll
    for (int nt = 0; nt < 3; ++nt)
      xl[nt] = *reinterpret_cast<const bf16x4*>(xpb + ((tmn + ntl[nt]) << 8) + fragoff);
    // gh = h @ Whh^T  (3 n-tiles: r,z,n for this wave's col group)
    f32x4 acc[3];
    #pragma unroll
    for (int nt = 0; nt < 3; ++nt) { f32x4 z = {0.f,0.f,0.f,0.f}; acc[nt] = z; }
    #pragma unroll
    for (int ks = 0; ks < 4; ++ks)
      #pragma unroll
      for (int nt = 0; nt < 3; ++nt)
        acc[nt] = __builtin_amdgcn_mfma_f32_16x16x32_bf16(a[ks], bw[nt][ks], acc[nt], 0, 0, 0);
    // gates (4 rows x 1 col per thread)
    #pragma unroll
    for (int i = 0; i < 4; ++i) {
      float r = sigm((float)xu[0][i] + acc[0][i]);          // bih+bhh folded into xp
      float z = sigm((float)xu[1][i] + acc[1][i]);
      float n = tanhx((float)xu[2][i] + r * (acc[2][i] + bn));  // bhh_n inside r*( )
      float hv = (1.f - z) * n + z * h_own[i];
      h_own[i] = hv;
      int m = g4*4 + i;
      h_lds[pb ^ 1][(js*64 + m + 16*jc3)*8 + je] = (bf16)hv;
    }
    __syncthreads();   // new-h visible to all
    // repacked X write (time-major): 16B per thread (first 4 waves) from h_lds[pb^1]
    if (tid < 256) {
      int mo = tid & 15, sc = tid >> 4;
      int s = sc >> 2, c3 = sc & 3;
      bf16x8 v = *reinterpret_cast<const bf16x8*>(&h_lds[pb ^ 1][s*512 + c3*128 + mo*8]);
      *reinterpret_cast<bf16x8*>(xout + ((size_t)tc*2048 + b0 + mo)*256 + d*128 + s*32 + c3*8) = v;
    }
  };

  for (int tw = 0; tw < len; ++tw) {
    if (tw & 1) step(xb, xa, tw, 1);
    else        step(xa, xb, tw, 0);
  }
  // persist h state
  #pragma unroll
  for (int i = 0; i < 4; ++i)
    hst[((size_t)d*2048 + b0 + g4*4 + i)*128 + j] = h_own[i];
}

// ---------------- final linear ----------------
__global__ void final_k(const bf16* __restrict__ hs, const float* __restrict__ lw,
                        const float* __restrict__ lb, float* __restrict__ out) {
  __shared__ float wsm[768];
  int tid = threadIdx.x;
  for (int i = tid; i < 768; i += 256) wsm[i] = lw[i];
  __syncthreads();
  int idx = blockIdx.x * 256 + tid;           // 0..139263  (b*68 + t)
  int b = idx / 68, t = idx % 68;
  const bf16* row = hs + ((size_t)t*2048 + b) * 256;   // time-major X
  float a0 = lb[0], a1 = lb[1], a2 = lb[2];
  for (int j0 = 0; j0 < 256; j0 += 8) {
    bf16x8 v = *reinterpret_cast<const bf16x8*>(row + j0);
    #pragma unroll
    for (int e = 0; e < 8; ++e) {
      float f = (float)v[e];
      a0 += f * wsm[(j0 + e)*3 + 0];
      a1 += f * wsm[(j0 + e)*3 + 1];
      a2 += f * wsm[(j0 + e)*3 + 2];
    }
  }
  out[(size_t)idx*3 + 0] = a0;
  out[(size_t)idx*3 + 1] = a1;
  out[(size_t)idx*3 + 2] = a2;
}

// ---------------- launch ----------------
extern "C" void kernel_launch(void* const* d_in, const int* in_sizes, int n_in,
                              void* d_out, int out_size, void* d_ws, size_t ws_size,
                              hipStream_t stream) {
  const int*   seq   = (const int*)d_in[0];
  const int*   str   = (const int*)d_in[1];
  const int*   lp    = (const int*)d_in[2];
  const float* table = (const float*)d_in[3];
  const float* w_ih  = (const float*)d_in[4];
  const float* w_hh  = (const float*)d_in[5];
  const float* b_ih  = (const float*)d_in[6];
  const float* b_hh  = (const float*)d_in[7];
  const float* lw    = (const float*)d_in[8];
  const float* lb    = (const float*)d_in[9];
  float* out = (float*)d_out;
  char* ws = (char*)d_ws;

  // ---- layout ----
  const size_t xsz    = (size_t)M_ * 256 * 2;        // 112,197,632 (X, time-major)
  const size_t shlosz = (size_t)54*2048*128*2;       // 28,311,552
  const size_t shhisz = (size_t)53*2048*128*2;       // 27,787,264
  const size_t wihsz  = (size_t)9*12*6*8*64*8 * 2;   // 5,308,416
  const size_t whhsz  = (size_t)9*2*4*24*64*8 * 2;   // 1,769,472
  const size_t biassz = 9*768*4, bhhnsz = 9*256*4;
  const size_t hstsz  = (size_t)2*2048*128*4;        // 2,097,152
  const size_t fixed  = xsz + shlosz + shhisz + wihsz + whhsz + biassz + bhhnsz + hstsz;
  int W = 32;
  while (W > 8 && fixed + (size_t)2*2048*W*384*2 > ws_size) W -= 8;
  const size_t xpwsz = (size_t)2*2048*W*384*2;

  size_t off = 0;
  bf16* X    = (bf16*)(ws + off); off += xsz;
  bf16* XPW  = (bf16*)(ws + off); off += xpwsz;
  bf16* SHLO = (bf16*)(ws + off); off += shlosz;
  bf16* SHHI = (bf16*)(ws + off); off += shhisz;
  bf16* WIH  = (bf16*)(ws + off); off += wihsz;
  bf16* WHH  = (bf16*)(ws + off); off += whhsz;
  float* BIAS = (float*)(ws + off); off += biassz;
  float* BHHN = (float*)(ws + off); off += bhhnsz;
  float* HST  = (float*)(ws + off);

  hipLaunchKernelGGL(pack_wih_k,  dim3(2654208/256), dim3(256), 0, stream, w_ih, WIH);
  hipLaunchKernelGGL(pack_whh_k,  dim3(884736/256),  dim3(256), 0, stream, w_hh, WHH);
  hipLaunchKernelGGL(pack_bias_k, dim3(27),          dim3(256), 0, stream, b_ih, b_hh, BIAS, BHHN);

  const int phases = (107 + W - 1) / W;
  for (int gl = 0; gl < 9; ++gl) {
    if (gl != 0)
      hipLaunchKernelGGL(shadow_k, dim3(13696), dim3(256), 0, stream, X, SHLO, SHHI);
    for (int p = 0; p < phases; ++p) {
      int len = (107 - p*W < W) ? (107 - p*W) : W;
      int t0f = p*W;
      int t0b = 106 - p*W;
      if (gl == 0)
        hipLaunchKernelGGL(gemm_proj_k<1>, dim3(len*16, 2), dim3(256), 0, stream,
                           X, SHLO, SHHI, seq, str, lp, table,
                           WIH + (size_t)gl*294912, BIAS + gl*768, XPW, len, t0f, t0b);
      else
        hipLaunchKernelGGL(gemm_proj_k<0>, dim3(len*16, 2), dim3(256), 0, stream,
                           X, SHLO, SHHI, seq, str, lp, table,
                           WIH + (size_t)gl*294912, BIAS + gl*768, XPW, len, t0f, t0b);
      hipLaunchKernelGGL(scan_k, dim3(128, 2), dim3(512), 0, stream,
                         XPW, WHH + (size_t)gl*98304, BHHN + gl*256, X, HST,
                         len, t0f, t0b, (p == 0) ? 1 : 0);
    }
  }
  hipLaunchKernelGGL(final_k, dim3(544), dim3(256), 0, stream, X, lw, lb, out);
}